// Round 1
// baseline (82.211 us; speedup 1.0000x reference)
//
#include <hip/hip_runtime.h>

// Problem constants (reference: N=1024 nodes, D=256 feat, H=256 hidden)
#define NN 1024
#define DD 256
#define HH 256

// adj[i,j] = 0.5*(sigmoid(s_i + t_j + c) + sigmoid(s_j + t_i + c))
// where u = w1[:D]@w2, v = w1[D:]@w2, s = z@u, t = z@v, c = b1.w2 + b2.

// Kernel 1: one block of 256 threads. Thread d computes u[d], v[d]; block
// reduction computes c.
__global__ void prep_kernel(const float* __restrict__ w1, const float* __restrict__ b1,
                            const float* __restrict__ w2, const float* __restrict__ b2,
                            float* __restrict__ u, float* __restrict__ v,
                            float* __restrict__ c) {
    const int d = threadIdx.x;  // 0..255
    const float* r0 = w1 + (size_t)d * HH;
    const float* r1 = w1 + (size_t)(d + DD) * HH;
    float su = 0.f, sv = 0.f;
    #pragma unroll 4
    for (int h = 0; h < HH; h += 4) {
        float4 wv = *reinterpret_cast<const float4*>(w2 + h);
        float4 a0 = *reinterpret_cast<const float4*>(r0 + h);
        float4 a1 = *reinterpret_cast<const float4*>(r1 + h);
        su += a0.x * wv.x + a0.y * wv.y + a0.z * wv.z + a0.w * wv.w;
        sv += a1.x * wv.x + a1.y * wv.y + a1.z * wv.z + a1.w * wv.w;
    }
    u[d] = su;
    v[d] = sv;

    __shared__ float red[256];
    red[d] = b1[d] * w2[d];
    __syncthreads();
    for (int off = 128; off > 0; off >>= 1) {
        if (d < off) red[d] += red[d + off];
        __syncthreads();
    }
    if (d == 0) c[0] = red[0] + b2[0];
}

// Kernel 2: one wave (64 lanes) per row. Lane l covers z[row][4l..4l+3].
// grid = N/4 blocks of 256 threads (4 waves/block).
__global__ void rows_kernel(const float* __restrict__ z, const float* __restrict__ u,
                            const float* __restrict__ v, float* __restrict__ s,
                            float* __restrict__ t) {
    const int wave = threadIdx.x >> 6;
    const int lane = threadIdx.x & 63;
    const int row = blockIdx.x * 4 + wave;
    const float4 zf = reinterpret_cast<const float4*>(z + (size_t)row * DD)[lane];
    const float4 uf = reinterpret_cast<const float4*>(u)[lane];
    const float4 vf = reinterpret_cast<const float4*>(v)[lane];
    float ds = zf.x * uf.x + zf.y * uf.y + zf.z * uf.z + zf.w * uf.w;
    float dt = zf.x * vf.x + zf.y * vf.y + zf.z * vf.z + zf.w * vf.w;
    #pragma unroll
    for (int off = 32; off > 0; off >>= 1) {
        ds += __shfl_down(ds, off);
        dt += __shfl_down(dt, off);
    }
    if (lane == 0) {
        s[row] = ds;
        t[row] = dt;
    }
}

__device__ __forceinline__ float sigmoidf(float x) {
    return 1.f / (1.f + __expf(-x));
}

// Kernel 3: each thread writes one float4 of out (4 consecutive j).
// grid = N*N/4/256 = 1024 blocks.
__global__ void out_kernel(const float* __restrict__ s, const float* __restrict__ t,
                           const float* __restrict__ c, float* __restrict__ out) {
    const float cc = c[0];
    const int tid = blockIdx.x * blockDim.x + threadIdx.x;  // 0..N*N/4-1
    const int i = tid >> 8;        // N/4 = 256 quads per row
    const int j0 = (tid & 255) * 4;
    const float si = s[i] + cc;
    const float ti = t[i] + cc;
    const float4 tj = *reinterpret_cast<const float4*>(t + j0);
    const float4 sj = *reinterpret_cast<const float4*>(s + j0);
    float4 r;
    r.x = 0.5f * (sigmoidf(si + tj.x) + sigmoidf(sj.x + ti));
    r.y = 0.5f * (sigmoidf(si + tj.y) + sigmoidf(sj.y + ti));
    r.z = 0.5f * (sigmoidf(si + tj.z) + sigmoidf(sj.z + ti));
    r.w = 0.5f * (sigmoidf(si + tj.w) + sigmoidf(sj.w + ti));
    reinterpret_cast<float4*>(out)[tid] = r;
}

extern "C" void kernel_launch(void* const* d_in, const int* in_sizes, int n_in,
                              void* d_out, int out_size, void* d_ws, size_t ws_size,
                              hipStream_t stream) {
    const float* z  = (const float*)d_in[0];
    const float* w1 = (const float*)d_in[1];
    const float* b1 = (const float*)d_in[2];
    const float* w2 = (const float*)d_in[3];
    const float* b2 = (const float*)d_in[4];
    float* out = (float*)d_out;

    // ws layout (floats): u[256] | v[256] | s[1024] | t[1024] | c[1]
    float* u = (float*)d_ws;
    float* v = u + DD;
    float* s = v + DD;
    float* t = s + NN;
    float* c = t + NN;

    prep_kernel<<<1, 256, 0, stream>>>(w1, b1, w2, b2, u, v, c);
    rows_kernel<<<NN / 4, 256, 0, stream>>>(z, u, v, s, t);
    out_kernel<<<(NN * NN / 4) / 256, 256, 0, stream>>>(s, t, c, out);
}